// Round 1
// baseline (1188.327 us; speedup 1.0000x reference)
//
#include <hip/hip_runtime.h>
#include <hip/hip_bf16.h>
#include <math.h>

#define NUM_EXPERTS 8
#define NTOK 8192
#define CDIM 1024
#define FDIM 4096
#define MAXSLOTS 17408   /* 16384 slots + 8*128 pad */
#define MAXTILES 136

typedef __bf16 bf16x8 __attribute__((ext_vector_type(8)));
typedef float  f32x4  __attribute__((ext_vector_type(4)));

#define GPTR(p) ((const __attribute__((address_space(1))) unsigned int*)(p))
#define LPTR(p) ((__attribute__((address_space(3))) unsigned int*)(p))

__device__ __forceinline__ float gelu_exact(float v){
  return 0.5f * v * (1.0f + erff(v * 0.70710678118654752f));
}

// ---------------- router: logits -> top2 -> weights + counts ----------------
__global__ __launch_bounds__(256) void moe_router(
    const float* __restrict__ x, const float* __restrict__ gw,
    int2* __restrict__ topi, float2* __restrict__ topw, int* __restrict__ counts)
{
  int token = blockIdx.x * 4 + (threadIdx.x >> 6);
  int lane  = threadIdx.x & 63;
  int e = lane & 7, part = lane >> 3;
  const float* xr = x + (size_t)token * CDIM;
  float s = 0.f;
  int c0 = part * 128;
  for (int c = c0; c < c0 + 128; ++c) s += xr[c] * gw[c * 8 + e];
  s += __shfl_xor(s, 8); s += __shfl_xor(s, 16); s += __shfl_xor(s, 32);
  // every lane now holds the full logit for expert e = lane&7
  float m1 = s; int i1 = e;
  for (int off = 1; off < 8; off <<= 1){
    float ov = __shfl_xor(m1, off); int oi = __shfl_xor(i1, off);
    if (ov > m1 || (ov == m1 && oi < i1)){ m1 = ov; i1 = oi; }
  }
  float l2 = (e == i1) ? -INFINITY : s;
  float m2 = l2; int i2 = e;
  for (int off = 1; off < 8; off <<= 1){
    float ov = __shfl_xor(m2, off); int oi = __shfl_xor(i2, off);
    if (ov > m2 || (ov == m2 && oi < i2)){ m2 = ov; i2 = oi; }
  }
  if (lane == 0){
    float r = expf(m2 - m1);          // p2/p1
    float wa = 1.f / (1.f + r);
    topi[token] = make_int2(i1, i2);
    topw[token] = make_float2(wa, 1.f - wa);
    atomicAdd(&counts[i1], 1);
    atomicAdd(&counts[i2], 1);
  }
}

// ---------------- x fp32 -> bf16 ----------------
__global__ __launch_bounds__(256) void convert_x_kernel(
    const float* __restrict__ x, __hip_bfloat16* __restrict__ xb)
{
  int i = (blockIdx.x * 256 + threadIdx.x) * 4;
  float4 v = *(const float4*)(x + i);
  union { __hip_bfloat16 hh[4]; ushort4 u; } cv;
  cv.hh[0] = __float2bfloat16(v.x);
  cv.hh[1] = __float2bfloat16(v.y);
  cv.hh[2] = __float2bfloat16(v.z);
  cv.hh[3] = __float2bfloat16(v.w);
  *(ushort4*)(xb + i) = cv.u;
}

// ---------------- weight transpose+convert: [z][R][Cc] fp32 -> [z][Cc][R] bf16 ----------------
__global__ __launch_bounds__(256) void transpose_bf16_kernel(
    const float* __restrict__ in, __hip_bfloat16* __restrict__ outp, int R, int Cc)
{
  __shared__ float tile[32][33];
  const size_t msz = (size_t)R * Cc;
  const float* inm = in + (size_t)blockIdx.z * msz;
  __hip_bfloat16* outm = outp + (size_t)blockIdx.z * msz;
  int r0 = blockIdx.y * 32, c0 = blockIdx.x * 32;
  int tx = threadIdx.x, ty = threadIdx.y;  // 32 x 8
  for (int yy = 0; yy < 32; yy += 8)
    tile[ty + yy][tx] = inm[(size_t)(r0 + ty + yy) * Cc + c0 + tx];
  __syncthreads();
  for (int yy = 0; yy < 32; yy += 8)
    outm[(size_t)(c0 + ty + yy) * R + r0 + tx] = __float2bfloat16(tile[tx][ty + yy]);
}

// ---------------- scan: expert offsets (128-aligned), tile table, pad fill ----------------
__global__ void scan_kernel(const int* __restrict__ counts, int* cursors, int* num_tiles,
    int* tile_expert, int* tile_slotbase, int* slot_token, float* slot_weight)
{
  int t = threadIdx.x;
  if (t == 0){
    int base = 0, T = 0;
    for (int e = 0; e < NUM_EXPERTS; ++e){
      cursors[e] = base;
      int nt = (counts[e] + 127) >> 7;
      for (int i = 0; i < nt; ++i){ tile_expert[T] = e; tile_slotbase[T] = base + i * 128; ++T; }
      base += nt << 7;
    }
    *num_tiles = T;
  }
  for (int i = t; i < MAXSLOTS; i += 256){ slot_token[i] = 0; slot_weight[i] = 0.f; }
}

// ---------------- assign (token,k) -> slot ----------------
__global__ void assign_kernel(const int2* __restrict__ topi, const float2* __restrict__ topw,
    int* cursors, int* slot_token, float* slot_weight)
{
  int token = blockIdx.x * 256 + threadIdx.x;
  int2 ii = topi[token];
  float2 ww = topw[token];
  int p0 = atomicAdd(&cursors[ii.x], 1);
  slot_token[p0] = token; slot_weight[p0] = ww.x;
  int p1 = atomicAdd(&cursors[ii.y], 1);
  slot_token[p1] = token; slot_weight[p1] = ww.y;
}

// ---------------- GEMM1: h = gelu(X[slots] @ w1[e]),  A gathered, B = w1t[e][f][c] ----------------
__global__ __launch_bounds__(256) void gemm1_kernel(
    const __hip_bfloat16* __restrict__ xbf, const __hip_bfloat16* __restrict__ w1t,
    __hip_bfloat16* __restrict__ h, const int* __restrict__ num_tiles,
    const int* __restrict__ tile_expert, const int* __restrict__ tile_slotbase,
    const int* __restrict__ slot_token)
{
  __shared__ __align__(16) __hip_bfloat16 As[128 * 64];
  __shared__ __align__(16) __hip_bfloat16 Bs[128 * 64];
  const int tm = blockIdx.y;
  if (tm >= *num_tiles) return;
  const int e = tile_expert[tm];
  const int sbase = tile_slotbase[tm];
  const int n0 = blockIdx.x * 128;
  const int t = threadIdx.x;
  const int cl = t & 7;
  const __hip_bfloat16* w1e = w1t + (size_t)e * FDIM * CDIM;
  const __hip_bfloat16* aptr[4];
  const __hip_bfloat16* bptr[4];
#pragma unroll
  for (int j = 0; j < 4; ++j){
    int r = j * 32 + (t >> 3);
    int cg = cl ^ (r & 7);
    int tok = slot_token[sbase + r];
    aptr[j] = xbf + (size_t)tok * CDIM + cg * 8;
    bptr[j] = w1e + (size_t)(n0 + r) * CDIM + cg * 8;
  }
  char* asml = (char*)As + t * 16;
  char* bsml = (char*)Bs + t * 16;

  f32x4 acc[4][4] = {};
  const int lane = t & 63, wv = t >> 6;
  const int wm = (wv >> 1) * 64, wn = (wv & 1) * 64;
  const int lrow = lane & 15, quad = lane >> 4;

  for (int k0 = 0; k0 < CDIM; k0 += 64){
    __syncthreads();
#pragma unroll
    for (int j = 0; j < 4; ++j){
      __builtin_amdgcn_global_load_lds(GPTR(aptr[j] + k0), LPTR(asml + j * 4096), 16, 0, 0);
      __builtin_amdgcn_global_load_lds(GPTR(bptr[j] + k0), LPTR(bsml + j * 4096), 16, 0, 0);
    }
    __syncthreads();
#pragma unroll
    for (int kk = 0; kk < 2; ++kk){
      bf16x8 af[4], bfr[4];
#pragma unroll
      for (int i = 0; i < 4; ++i){
        int ar = wm + i * 16 + lrow;
        int ac = (kk * 4 + quad) ^ (ar & 7);
        af[i] = *(const bf16x8*)((const char*)As + ar * 128 + ac * 16);
        int br = wn + i * 16 + lrow;
        int bc = (kk * 4 + quad) ^ (br & 7);
        bfr[i] = *(const bf16x8*)((const char*)Bs + br * 128 + bc * 16);
      }
#pragma unroll
      for (int i = 0; i < 4; ++i)
#pragma unroll
        for (int j = 0; j < 4; ++j)
          acc[i][j] = __builtin_amdgcn_mfma_f32_16x16x32_bf16(af[i], bfr[j], acc[i][j], 0, 0, 0);
    }
  }
#pragma unroll
  for (int i = 0; i < 4; ++i){
#pragma unroll
    for (int r = 0; r < 4; ++r){
      int row = wm + i * 16 + quad * 4 + r;
      __hip_bfloat16* hrow = h + (size_t)(sbase + row) * FDIM + n0 + wn;
#pragma unroll
      for (int j = 0; j < 4; ++j)
        hrow[j * 16 + lrow] = __float2bfloat16(gelu_exact(acc[i][j][r]));
    }
  }
}

// ---------------- GEMM2: out[token] += w * (h[slots] @ w2[e]),  B = w2t[e][c][f] ----------------
__global__ __launch_bounds__(256) void gemm2_kernel(
    const __hip_bfloat16* __restrict__ h, const __hip_bfloat16* __restrict__ w2t,
    float* __restrict__ out, const int* __restrict__ num_tiles,
    const int* __restrict__ tile_expert, const int* __restrict__ tile_slotbase,
    const int* __restrict__ slot_token, const float* __restrict__ slot_weight)
{
  __shared__ __align__(16) __hip_bfloat16 As[128 * 64];
  __shared__ __align__(16) __hip_bfloat16 Bs[128 * 64];
  const int tm = blockIdx.y;
  if (tm >= *num_tiles) return;
  const int e = tile_expert[tm];
  const int sbase = tile_slotbase[tm];
  const int n0 = blockIdx.x * 128;
  const int t = threadIdx.x;
  const int cl = t & 7;
  const __hip_bfloat16* w2e = w2t + (size_t)e * CDIM * FDIM;
  const __hip_bfloat16* aptr[4];
  const __hip_bfloat16* bptr[4];
#pragma unroll
  for (int j = 0; j < 4; ++j){
    int r = j * 32 + (t >> 3);
    int cg = cl ^ (r & 7);
    aptr[j] = h   + (size_t)(sbase + r) * FDIM + cg * 8;
    bptr[j] = w2e + (size_t)(n0 + r)   * FDIM + cg * 8;
  }
  char* asml = (char*)As + t * 16;
  char* bsml = (char*)Bs + t * 16;

  f32x4 acc[4][4] = {};
  const int lane = t & 63, wv = t >> 6;
  const int wm = (wv >> 1) * 64, wn = (wv & 1) * 64;
  const int lrow = lane & 15, quad = lane >> 4;

  for (int k0 = 0; k0 < FDIM; k0 += 64){
    __syncthreads();
#pragma unroll
    for (int j = 0; j < 4; ++j){
      __builtin_amdgcn_global_load_lds(GPTR(aptr[j] + k0), LPTR(asml + j * 4096), 16, 0, 0);
      __builtin_amdgcn_global_load_lds(GPTR(bptr[j] + k0), LPTR(bsml + j * 4096), 16, 0, 0);
    }
    __syncthreads();
#pragma unroll
    for (int kk = 0; kk < 2; ++kk){
      bf16x8 af[4], bfr[4];
#pragma unroll
      for (int i = 0; i < 4; ++i){
        int ar = wm + i * 16 + lrow;
        int ac = (kk * 4 + quad) ^ (ar & 7);
        af[i] = *(const bf16x8*)((const char*)As + ar * 128 + ac * 16);
        int br = wn + i * 16 + lrow;
        int bc = (kk * 4 + quad) ^ (br & 7);
        bfr[i] = *(const bf16x8*)((const char*)Bs + br * 128 + bc * 16);
      }
#pragma unroll
      for (int i = 0; i < 4; ++i)
#pragma unroll
        for (int j = 0; j < 4; ++j)
          acc[i][j] = __builtin_amdgcn_mfma_f32_16x16x32_bf16(af[i], bfr[j], acc[i][j], 0, 0, 0);
    }
  }
#pragma unroll
  for (int i = 0; i < 4; ++i){
#pragma unroll
    for (int r = 0; r < 4; ++r){
      int row = wm + i * 16 + quad * 4 + r;
      int slot = sbase + row;
      int tok = slot_token[slot];
      float wgt = slot_weight[slot];
      float* orow = out + (size_t)tok * CDIM + n0 + wn;
#pragma unroll
      for (int j = 0; j < 4; ++j)
        atomicAdd(&orow[j * 16 + lrow], wgt * acc[i][j][r]);
    }
  }
}

// ---------------- slow-but-correct fallback (ws too small) ----------------
__global__ __launch_bounds__(256) void naive_kernel(
    const float* __restrict__ x, const float* __restrict__ w1, const float* __restrict__ w2,
    const int2* __restrict__ topi, const float2* __restrict__ topw, float* __restrict__ out)
{
  __shared__ float xs[CDIM];
  __shared__ float hs[FDIM];
  int token = blockIdx.x;
  int t = threadIdx.x;
  for (int i = t; i < CDIM; i += 256) xs[i] = x[(size_t)token * CDIM + i];
  float acc[4] = {0.f, 0.f, 0.f, 0.f};
  int2 ei = topi[token]; float2 ew = topw[token];
  int elist[2] = {ei.x, ei.y}; float wlist[2] = {ew.x, ew.y};
  for (int kk = 0; kk < 2; ++kk){
    int e = elist[kk]; float wgt = wlist[kk];
    __syncthreads();
    for (int f = t; f < FDIM; f += 256){
      const float* wcol = w1 + (size_t)e * CDIM * FDIM + f;
      float s = 0.f;
      for (int c = 0; c < CDIM; ++c) s += xs[c] * wcol[(size_t)c * FDIM];
      hs[f] = gelu_exact(s);
    }
    __syncthreads();
    for (int ii = 0; ii < 4; ++ii){
      int c = ii * 256 + t;
      const float* w2col = w2 + (size_t)e * FDIM * CDIM + c;
      float s = 0.f;
      for (int f = 0; f < FDIM; ++f) s += hs[f] * w2col[(size_t)f * CDIM];
      acc[ii] += wgt * s;
    }
  }
  for (int ii = 0; ii < 4; ++ii) out[(size_t)token * CDIM + ii * 256 + t] = acc[ii];
}

extern "C" void kernel_launch(void* const* d_in, const int* in_sizes, int n_in,
                              void* d_out, int out_size, void* d_ws, size_t ws_size,
                              hipStream_t stream)
{
  const float* x  = (const float*)d_in[0];
  const float* gw = (const float*)d_in[1];
  const float* w1 = (const float*)d_in[2];
  const float* w2 = (const float*)d_in[3];
  float* out = (float*)d_out;
  char* ws = (char*)d_ws;

  int*    counts        = (int*)(ws + 0);
  int*    cursors       = (int*)(ws + 32);
  int*    num_tiles     = (int*)(ws + 64);
  int*    tile_expert   = (int*)(ws + 256);
  int*    tile_slotbase = (int*)(ws + 1024);
  int2*   topi          = (int2*)(ws + 4096);
  float2* topw          = (float2*)(ws + 4096 + 65536);
  int*    slot_token    = (int*)(ws + 135168);
  float*  slot_weight   = (float*)(ws + 204800);
  const size_t XBF_OFF = 1u << 20;
  const size_t W1T_OFF = XBF_OFF + (size_t)NTOK * CDIM * 2;                    // 17825792
  const size_t W2T_OFF = W1T_OFF + (size_t)NUM_EXPERTS * CDIM * FDIM * 2;      // +67108864
  const size_t H_OFF   = W2T_OFF + (size_t)NUM_EXPERTS * CDIM * FDIM * 2;
  const size_t NEED    = H_OFF + (size_t)MAXSLOTS * FDIM * 2;                  // ~295 MB
  __hip_bfloat16* xbf = (__hip_bfloat16*)(ws + XBF_OFF);
  __hip_bfloat16* w1t = (__hip_bfloat16*)(ws + W1T_OFF);
  __hip_bfloat16* w2t = (__hip_bfloat16*)(ws + W2T_OFF);
  __hip_bfloat16* h   = (__hip_bfloat16*)(ws + H_OFF);

  hipMemsetAsync(ws, 0, 4096, stream);
  hipMemsetAsync(d_out, 0, (size_t)out_size * sizeof(float), stream);

  moe_router<<<NTOK / 4, 256, 0, stream>>>(x, gw, topi, topw, counts);

  if (ws_size >= NEED){
    convert_x_kernel<<<NTOK * CDIM / (4 * 256), 256, 0, stream>>>(x, xbf);
    transpose_bf16_kernel<<<dim3(FDIM / 32, CDIM / 32, NUM_EXPERTS), dim3(32, 8), 0, stream>>>(w1, w1t, CDIM, FDIM);
    transpose_bf16_kernel<<<dim3(CDIM / 32, FDIM / 32, NUM_EXPERTS), dim3(32, 8), 0, stream>>>(w2, w2t, FDIM, CDIM);
    scan_kernel<<<1, 256, 0, stream>>>(counts, cursors, num_tiles, tile_expert, tile_slotbase, slot_token, slot_weight);
    assign_kernel<<<NTOK / 256, 256, 0, stream>>>(topi, topw, cursors, slot_token, slot_weight);
    gemm1_kernel<<<dim3(FDIM / 128, MAXTILES), 256, 0, stream>>>(xbf, w1t, h, num_tiles, tile_expert, tile_slotbase, slot_token);
    gemm2_kernel<<<dim3(CDIM / 128, MAXTILES), 256, 0, stream>>>(h, w2t, out, num_tiles, tile_expert, tile_slotbase, slot_token, slot_weight);
  } else {
    naive_kernel<<<NTOK, 256, 0, stream>>>(x, w1, w2, topi, topw, out);
  }
}